// Round 11
// baseline (405.287 us; speedup 1.0000x reference)
//
#include <hip/hip_runtime.h>
#include <math.h>

// Problem constants
#define HO 512
#define WO 512
#define HI 128
#define WI 128
#define CC 64      // channels
#define BS 2       // batch
#define NPX 64     // pixels per block (one row segment)
#define NT 256     // threads per block

// d_ws layout:
//   [0)              bf16 packed weights: w2p then w3p
//   [XT_BYTE_OFF)    x_t padded transpose: float [130][130][64][2]  (c-major, b innermost)
#define W2P_ELEMS (16 * 2 * 64 * 8)      // [nt=16][ks=2][lane=64][j=8]  = 16384
#define W3P_ELEMS (36 * 8 * 64 * 8)      // [nt=36][ks=8][lane=64][j=8]  = 147456
#define TOTALW    (W2P_ELEMS + W3P_ELEMS)       // 163840
#define XT_ELEM_OFF TOTALW                      // in shorts (327680 B, 16B aligned)
#define NBORDER4  16512                          // border float4s: 2*130*32 + 128*2*32

typedef __attribute__((ext_vector_type(8))) short short8;
typedef __attribute__((ext_vector_type(4))) float float4v;
typedef __attribute__((ext_vector_type(2))) float float2v;

__device__ __forceinline__ unsigned short f2bf(float f) {
    unsigned u = __builtin_bit_cast(unsigned, f);
    unsigned r = (u + 0x7FFFu + ((u >> 16) & 1u)) >> 16;   // RNE
    return (unsigned short)r;
}

// ---------------- single prepack kernel (R10, proven) ----------------
// tid [0, 262144): x -> x_t[(h+1)][(w+1)][c][b] interior transpose
// tid [262144, 524288): weights bf16 pack (natural W3 k-order) +
//                       border-only x_t zero (gathers touch a 1-cell halo).
__global__ void prepack_all(const float* __restrict__ x,
                            const float* __restrict__ W2,
                            const float* __restrict__ W3,
                            unsigned short* __restrict__ wsp,
                            float* __restrict__ xt) {
    const int tid = blockIdx.x * blockDim.x + threadIdx.x;   // 2048*256
    if (tid < 262144) {
        const int pos = tid & 16383;          // h*128+w
        const int g   = tid >> 14;            // channel group: 4 ch x 2 batches
        const int h = pos >> 7, w = pos & 127;
        const float* src = x + pos;
        float a0[4], a1[4];
        #pragma unroll
        for (int j = 0; j < 4; ++j) a0[j] = src[(size_t)(g * 4 + j) * (HI * WI)];        // b=0
        #pragma unroll
        for (int j = 0; j < 4; ++j) a1[j] = src[(size_t)(CC + g * 4 + j) * (HI * WI)];   // b=1
        float* dst = xt + ((h + 1) * 130 + (w + 1)) * 128 + g * 8;
        *(float4v*)dst       = (float4v){a0[0], a1[0], a0[1], a1[1]};
        *(float4v*)(dst + 4) = (float4v){a0[2], a1[2], a0[3], a1[3]};
        return;
    }
    const int idx = tid - 262144;             // aux slots, single pass
    if (idx < W2P_ELEMS) {
        int j = idx & 7, lane = (idx >> 3) & 63, rest = idx >> 9;
        int ks = rest & 1, nt = rest >> 1;
        int n = nt * 16 + (lane & 15);
        int k = ks * 32 + (lane >> 4) * 8 + j;
        wsp[idx] = f2bf(W2[n * 64 + k]);      // W2: [256][64]
    } else if (idx < TOTALW) {
        int i2 = idx - W2P_ELEMS;
        int j = i2 & 7, lane = (i2 >> 3) & 63, rest = i2 >> 9;
        int ks = rest & 7, nt = rest >> 3;    // nt = tap*4+chtile
        int tap = nt >> 2, ct = nt & 3;
        int row = (ct * 16 + (lane & 15)) * 9 + tap;   // < 576
        int k = ks * 32 + (lane >> 4) * 8 + j;         // natural k-order
        wsp[idx] = f2bf(W3[row * 256 + k]);   // W3: [576][256]
    } else if (idx < TOTALW + NBORDER4) {
        int a = idx - TOTALW;                 // border float4 index
        int cell;                             // h*130+w of a border cell
        if (a < 2 * 130 * 32) {               // rows h=0 and h=129 (full)
            int r = a / (130 * 32);
            int rest = a - r * (130 * 32);
            cell = (r * 129) * 130 + (rest >> 5);
            a = rest;
        } else {                              // cols w=0 and w=129, h=1..128
            int a2 = a - 2 * 130 * 32;
            int h = 1 + (a2 >> 6);            // 64 float4 per h (2 cells x 32)
            int rest = a2 & 63;
            cell = h * 130 + (rest >> 5) * 129;
            a = rest;
        }
        float4v z = {0.f, 0.f, 0.f, 0.f};
        *(float4v*)(xt + (size_t)cell * 128 + (a & 31) * 4) = z;
    }
}

// ---------------- fused main kernel ----------------
// R11 = R4 (proven 285us) with stage 3 made BARRIER-FREE:
//  - sOut transpose tile DELETED; each lane stores its 4 consecutive px of
//    channel c as one float4 (64B full sectors; R1 measured the cost: +19MB
//    WRITE only). All data is lane-private -> no cross-lane handoff needed.
//  - sH2 is WAVE-PRIVATE (wave w writes rows m0..m0+15 in stage 2, reads the
//    same rows in stage 3) -> no barrier after stage 2 either.
//  - sH1 unioned UNDER sH2 (a-frags hoisted to regs + one barrier, the
//    R9-proven pattern) -> LDS 35072 B.
// Net: 7 barriers -> 3, all BEFORE stage 3. The gather/softmax/MFMA phase has
// zero __syncthreads -> zero forced vmcnt(0)+lgkmcnt(0) drains; gathers of
// ct overlap ct+1's MFMA stream and waves never convoy on the slowest
// random-gather straggler. R4's stage-1/2/3 arithmetic is untouched.
__global__ __launch_bounds__(NT, 3)
void fused_main(const float* __restrict__ xt, const float* __restrict__ pose,
                const float* __restrict__ W1, const float* __restrict__ b1,
                const float* __restrict__ b2, const float* __restrict__ b3,
                const int* __restrict__ iY, const int* __restrict__ iX,
                const unsigned short* __restrict__ wsp,
                float* __restrict__ out)
{
    // Manual LDS layout (35072 B). sH1 overlaps sH2 (sequentially dead).
    __shared__ char smem[33792 + 768 + 512];
    unsigned short (*sH2)[264] = (unsigned short (*)[264])&smem[0];        // 33792 B
    unsigned short (*sH1)[72]  = (unsigned short (*)[72])&smem[0];         // 9216 B (union)
    float (*sP)[NPX]           = (float (*)[NPX])&smem[33792];             // 768 B
    int* sIY                   = (int*)&smem[34560];                       // 256 B
    int* sIX                   = (int*)&smem[34816];                       // 256 B

    const int t = threadIdx.x;
    const int pixBase = blockIdx.x * NPX;    // 64 px within one output row
    const int y  = pixBase / WO;
    const int x0 = pixBase % WO;

    if (t < 192) sP[t >> 6][t & 63] = pose[(t >> 6) * (HO * WO) + pixBase + (t & 63)];
    if (t < 64) sIY[t] = iY[pixBase + t];
    else if (t < 128) sIX[t - 64] = iX[pixBase + t - 64];
    __syncthreads();                          // barrier 1

    // ---- stage 1: h1 = relu(W1 @ p + b1)  (cross-wave: wave = feature grp)
    {
        const int p  = t & 63;
        const int og = t >> 6;
        const float p0 = sP[0][p], p1 = sP[1][p], p2 = sP[2][p];
        #pragma unroll
        for (int i = 0; i < 16; i += 2) {
            const int o = og * 16 + i;
            float a0 = fmaf(W1[o * 3 + 2], p2, fmaf(W1[o * 3 + 1], p1, fmaf(W1[o * 3 + 0], p0, b1[o])));
            float a1 = fmaf(W1[o * 3 + 5], p2, fmaf(W1[o * 3 + 4], p1, fmaf(W1[o * 3 + 3], p0, b1[o + 1])));
            a0 = fmaxf(a0, 0.f); a1 = fmaxf(a1, 0.f);
            unsigned pack = (unsigned)f2bf(a0) | ((unsigned)f2bf(a1) << 16);
            *(unsigned*)&sH1[p][o] = pack;
        }
    }
    __syncthreads();                          // barrier 2

    const int wv = t >> 6, l = t & 63, lm = l & 15, lq = l >> 4;
    const int m0 = wv * 16;                  // wave's pixel base

    // hoist a-frags (cross-wave sH1 reads) into regs, then release sH1
    short8 a0 = *(const short8*)&sH1[m0 + lm][0  + lq * 8];
    short8 a1 = *(const short8*)&sH1[m0 + lm][32 + lq * 8];
    __syncthreads();                          // barrier 3 (last one!)
                                              // sH2 writes may now clobber sH1

    // ---- stage 2: h2 = relu(h1 @ W2^T + b2)  [16px x 256] per wave (R4)
    //      D: col(lm)=feature, row(lq*4+r)=px -> writes wave-private rows.
    {
        const short8* w2f = (const short8*)wsp;
        #pragma unroll 4
        for (int nt = 0; nt < 16; ++nt) {
            float4v acc = {0.f, 0.f, 0.f, 0.f};
            short8 bf0 = w2f[(nt * 2 + 0) * 64 + l];
            short8 bf1 = w2f[(nt * 2 + 1) * 64 + l];
            acc = __builtin_amdgcn_mfma_f32_16x16x32_bf16(a0, bf0, acc, 0, 0, 0);
            acc = __builtin_amdgcn_mfma_f32_16x16x32_bf16(a1, bf1, acc, 0, 0, 0);
            const float bv = b2[nt * 16 + lm];
            #pragma unroll
            for (int r = 0; r < 4; ++r)
                sH2[m0 + lq * 4 + r][nt * 16 + lm] = f2bf(fmaxf(acc[r] + bv, 0.f));
        }
    }
    // NO barrier: sH2 rows m0..m0+15 are wave-private (written and read by
    // this wave only). Same-wave ds ordering is guaranteed by lgkmcnt.

    // per-lane pixel bases into x_t (pixels p = m0 + lq*4 + r)
    int pbase[4];
    #pragma unroll
    for (int r = 0; r < 4; ++r) {
        const int p = m0 + lq * 4 + r;
        pbase[r] = ((sIY[p] + 1) * 130 + (sIX[p] + 1)) * 128;
    }
    const int koff[9] = {-131 * 128, -130 * 128, -129 * 128,
                         -1 * 128,   0,          1 * 128,
                         129 * 128,  130 * 128,  131 * 128};
    const short8* w3f = (const short8*)(wsp + W2P_ELEMS);

    // ---- stage 3 (barrier-free): 4 chtiles of 16 ch; 9 taps in registers
    for (int ct = 0; ct < 4; ++ct) {
        float4v accs[9];
        #pragma unroll
        for (int tap = 0; tap < 9; ++tap) accs[tap] = (float4v){0.f, 0.f, 0.f, 0.f};

        #pragma unroll 2
        for (int ks = 0; ks < 8; ++ks) {
            short8 a = *(const short8*)&sH2[m0 + lm][ks * 32 + lq * 8];
            #pragma unroll
            for (int tap = 0; tap < 9; ++tap) {
                short8 b = w3f[(((tap << 2) | ct) * 8 + ks) * 64 + l];
                accs[tap] = __builtin_amdgcn_mfma_f32_16x16x32_bf16(a, b, accs[tap], 0, 0, 0);
            }
        }

        const int c = ct * 16 + lm;          // this lane's channel
        float bv[9];
        #pragma unroll
        for (int tap = 0; tap < 9; ++tap) bv[tap] = b3[c * 9 + tap];

        float ob0[4], ob1[4];
        #pragma unroll
        for (int r = 0; r < 4; ++r) {
            float lg[9];
            #pragma unroll
            for (int tap = 0; tap < 9; ++tap) lg[tap] = accs[tap][r] + bv[tap];
            float mx = lg[0];
            #pragma unroll
            for (int tap = 1; tap < 9; ++tap) mx = fmaxf(mx, lg[tap]);
            const float* xb = xt + pbase[r] + 2 * c;
            float s = 0.f, o0 = 0.f, o1 = 0.f;
            #pragma unroll
            for (int tap = 0; tap < 9; ++tap) {
                const float ev = __expf(lg[tap] - mx);
                const float2v gg = *(const float2v*)(xb + koff[tap]);  // one 8B load: b=0,b=1
                s += ev;
                o0 = fmaf(ev, gg[0], o0);
                o1 = fmaf(ev, gg[1], o1);
            }
            const float inv = 1.f / s;
            ob0[r] = o0 * inv;
            ob1[r] = o1 * inv;
        }

        // direct lane-private stores: this lane owns px [m0+lq*4, +4) of
        // channel c -> one float4 per batch (64B full sectors; no LDS, no
        // barrier, no cross-lane traffic).
        const int px = x0 + m0 + lq * 4;
        float* op0 = out + ((size_t)c * HO + y) * WO + px;
        float* op1 = op0 + (size_t)CC * HO * WO;
        *(float4v*)op0 = (float4v){ob0[0], ob0[1], ob0[2], ob0[3]};
        *(float4v*)op1 = (float4v){ob1[0], ob1[1], ob1[2], ob1[3]};
    }
}

extern "C" void kernel_launch(void* const* d_in, const int* in_sizes, int n_in,
                              void* d_out, int out_size, void* d_ws, size_t ws_size,
                              hipStream_t stream) {
    const float* x    = (const float*)d_in[0];
    const float* pose = (const float*)d_in[1];
    const float* W1   = (const float*)d_in[2];
    const float* b1   = (const float*)d_in[3];
    const float* W2   = (const float*)d_in[4];
    const float* b2   = (const float*)d_in[5];
    const float* W3   = (const float*)d_in[6];
    const float* b3   = (const float*)d_in[7];
    const int*   iY   = (const int*)d_in[8];
    const int*   iX   = (const int*)d_in[9];
    float* out = (float*)d_out;
    unsigned short* wsp = (unsigned short*)d_ws;
    float* xt = (float*)((char*)d_ws + (size_t)XT_ELEM_OFF * sizeof(unsigned short));

    prepack_all<<<2048, NT, 0, stream>>>(x, W2, W3, wsp, xt);

    const int nblocks = (HO * WO) / NPX;   // 4096
    fused_main<<<nblocks, NT, 0, stream>>>(
        xt, pose, W1, b1, b2, b3, iY, iX, wsp, out);
}